// Round 1
// baseline (428.887 us; speedup 1.0000x reference)
//
#include <hip/hip_runtime.h>

typedef __bf16 bf16x8 __attribute__((ext_vector_type(8)));
typedef float f32x4 __attribute__((ext_vector_type(4)));

#define BATCH 4
#define SEQ   2048
#define DIM   1024
#define NH    16
#define HD    64

__device__ __forceinline__ unsigned short f2bf(float f) {
  union { float f; unsigned u; } v; v.f = f;
  unsigned u = v.u;
  u += 0x7FFF + ((u >> 16) & 1);   // round-to-nearest-even
  return (unsigned short)(u >> 16);
}

// ---------------- cast fp32 -> bf16, 8 elems/thread ----------------
__global__ __launch_bounds__(256) void cast_bf16_kernel(
    const float* __restrict__ in, unsigned short* __restrict__ out, int n8) {
  int i = blockIdx.x * 256 + threadIdx.x;
  if (i >= n8) return;
  const float4* p = (const float4*)in + (size_t)i * 2;
  float4 a = p[0], b = p[1];
  unsigned short r[8];
  r[0] = f2bf(a.x); r[1] = f2bf(a.y); r[2] = f2bf(a.z); r[3] = f2bf(a.w);
  r[4] = f2bf(b.x); r[5] = f2bf(b.y); r[6] = f2bf(b.z); r[7] = f2bf(b.w);
  *(uint4*)&out[(size_t)i * 8] = *(uint4*)r;
}

// ---------------- QKV projection GEMM --------------------------------
// C[m,n] = sum_k A[m,k]*W[n,k] + bias[n]; A=[8192,1024] bf16, W=[1024,1024] bf16.
// mode 0: store bf16 at [b,h,s,hd]; mode 1: store bf16 at [b,h,hd,s] (for V).
#define LDT 40   // padded LDS stride (elems) for 128x32 tiles
__global__ __launch_bounds__(256) void gemm_qkv(
    const unsigned short* __restrict__ A, const unsigned short* __restrict__ W,
    const float* __restrict__ bias, unsigned short* __restrict__ outp, int mode) {
  __shared__ unsigned short As[128 * LDT];
  __shared__ unsigned short Bs[128 * LDT];
  const int tid  = threadIdx.x;
  const int wave = tid >> 6;
  const int lane = tid & 63;
  const int lm   = lane & 15;
  const int qd   = lane >> 4;
  const int m0 = blockIdx.x * 128;
  const int n0 = blockIdx.y * 128;
  const int wm = (wave >> 1) * 64;
  const int wn = (wave & 1) * 64;

  const f32x4 zero = {0.f, 0.f, 0.f, 0.f};
  f32x4 acc[4][4];
#pragma unroll
  for (int i = 0; i < 4; ++i)
#pragma unroll
    for (int j = 0; j < 4; ++j) acc[i][j] = zero;

  const int ld_row = tid >> 2;        // 0..63
  const int ld_col = (tid & 3) * 8;   // 0,8,16,24

  for (int kt = 0; kt < DIM; kt += 32) {
    __syncthreads();
#pragma unroll
    for (int p = 0; p < 2; ++p) {
      int r = ld_row + p * 64;
      *(uint4*)&As[r * LDT + ld_col] = *(const uint4*)&A[(size_t)(m0 + r) * DIM + kt + ld_col];
      *(uint4*)&Bs[r * LDT + ld_col] = *(const uint4*)&W[(size_t)(n0 + r) * DIM + kt + ld_col];
    }
    __syncthreads();

    bf16x8 af[4], bfr[4];
#pragma unroll
    for (int i = 0; i < 4; ++i) af[i]  = *(const bf16x8*)&As[(wm + i * 16 + lm) * LDT + qd * 8];
#pragma unroll
    for (int j = 0; j < 4; ++j) bfr[j] = *(const bf16x8*)&Bs[(wn + j * 16 + lm) * LDT + qd * 8];
#pragma unroll
    for (int i = 0; i < 4; ++i)
#pragma unroll
      for (int j = 0; j < 4; ++j)
        acc[i][j] = __builtin_amdgcn_mfma_f32_16x16x32_bf16(af[i], bfr[j], acc[i][j], 0, 0, 0);
  }

  // epilogue: +bias, cast bf16, permuted store
#pragma unroll
  for (int j = 0; j < 4; ++j) {
    int col = n0 + wn + j * 16 + lm;       // n index
    float bb = bias[col];
    int h = col >> 6, hd = col & 63;
#pragma unroll
    for (int i = 0; i < 4; ++i) {
#pragma unroll
      for (int r = 0; r < 4; ++r) {
        int row = m0 + wm + i * 16 + qd * 4 + r;   // m index
        int b = row >> 11, s = row & 2047;
        float v = acc[i][j][r] + bb;
        size_t idx;
        if (mode == 0) idx = ((size_t)(b * NH + h) * SEQ + s) * HD + hd;
        else           idx = ((size_t)(b * NH + h) * HD + hd) * SEQ + s;
        outp[idx] = f2bf(v);
      }
    }
  }
}

// ---------------- flash attention ------------------------------------
// Q,K: [bh, s, hd] bf16.  V: [bh, hd, s] bf16.  out: [b, s, h*hd] fp32.
#define LDF 72   // padded LDS stride for 64x64 tiles
__global__ __launch_bounds__(256) void flash_kernel(
    const unsigned short* __restrict__ Qw, const unsigned short* __restrict__ Kw,
    const unsigned short* __restrict__ Vw, float* __restrict__ out) {
  __shared__ unsigned short Qs[64 * LDF];
  __shared__ unsigned short Ks[64 * LDF];
  __shared__ unsigned short Vs[64 * LDF];   // [hd][key]
  __shared__ unsigned short Ps[64 * LDF];   // [qrow][key]

  const int tid  = threadIdx.x;
  const int wave = tid >> 6;
  const int lane = tid & 63;
  const int lm   = lane & 15;
  const int qd   = lane >> 4;
  const int qt   = blockIdx.x;   // 0..31
  const int bh   = blockIdx.y;   // 0..63
  const int q0   = qt * 64;

  // load Q tile [64 x 64]
  {
    const int r = tid >> 3;           // 0..31
    const int c = (tid & 7) * 8;      // 0..56
    const unsigned short* src = Qw + (size_t)bh * (SEQ * HD) + (size_t)q0 * HD;
#pragma unroll
    for (int p = 0; p < 2; ++p) {
      int row = p * 32 + r;
      *(uint4*)&Qs[row * LDF + c] = *(const uint4*)&src[row * HD + c];
    }
  }

  const f32x4 zero = {0.f, 0.f, 0.f, 0.f};
  float mrun[4], lrun[4];
  f32x4 o[4];
#pragma unroll
  for (int r = 0; r < 4; ++r) { mrun[r] = -1e30f; lrun[r] = 0.f; o[r] = zero; }

  const unsigned short* Kbase = Kw + (size_t)bh * (SEQ * HD);
  const unsigned short* Vbase = Vw + (size_t)bh * (HD * SEQ);

  for (int kt = 0; kt < SEQ / 64; ++kt) {
    __syncthreads();
    {
      const int r = tid >> 3;
      const int c = (tid & 7) * 8;
#pragma unroll
      for (int p = 0; p < 2; ++p) {
        int row = p * 32 + r;
        *(uint4*)&Ks[row * LDF + c] = *(const uint4*)&Kbase[(size_t)(kt * 64 + row) * HD + c];
        *(uint4*)&Vs[row * LDF + c] = *(const uint4*)&Vbase[(size_t)row * SEQ + kt * 64 + c];
      }
    }
    __syncthreads();

    // S = Q K^T (16 rows per wave x 64 keys)
    bf16x8 qf[2];
#pragma unroll
    for (int h = 0; h < 2; ++h)
      qf[h] = *(const bf16x8*)&Qs[(wave * 16 + lm) * LDF + h * 32 + qd * 8];
    f32x4 s[4];
#pragma unroll
    for (int j = 0; j < 4; ++j) {
      s[j] = zero;
#pragma unroll
      for (int h = 0; h < 2; ++h) {
        bf16x8 kf = *(const bf16x8*)&Ks[(j * 16 + lm) * LDF + h * 32 + qd * 8];
        s[j] = __builtin_amdgcn_mfma_f32_16x16x32_bf16(qf[h], kf, s[j], 0, 0, 0);
      }
      s[j] *= 0.125f;   // 1/sqrt(64)
    }

    // row max (rows live at quad*4+reg; cols across the 16-lane group)
    float mx[4];
#pragma unroll
    for (int r = 0; r < 4; ++r)
      mx[r] = fmaxf(fmaxf(s[0][r], s[1][r]), fmaxf(s[2][r], s[3][r]));
#pragma unroll
    for (int d = 1; d < 16; d <<= 1)
#pragma unroll
      for (int r = 0; r < 4; ++r)
        mx[r] = fmaxf(mx[r], __shfl_xor(mx[r], d));

    float mnew[4], alpha[4], psum[4];
#pragma unroll
    for (int r = 0; r < 4; ++r) {
      mnew[r]  = fmaxf(mrun[r], mx[r]);
      alpha[r] = __expf(mrun[r] - mnew[r]);
      mrun[r]  = mnew[r];
      psum[r]  = 0.f;
    }

    // P = exp(s - m), write bf16 to LDS in [qrow][key] layout
#pragma unroll
    for (int j = 0; j < 4; ++j)
#pragma unroll
      for (int r = 0; r < 4; ++r) {
        float p = __expf(s[j][r] - mnew[r]);
        psum[r] += p;
        Ps[(wave * 16 + qd * 4 + r) * LDF + j * 16 + lm] = f2bf(p);
      }
#pragma unroll
    for (int d = 1; d < 16; d <<= 1)
#pragma unroll
      for (int r = 0; r < 4; ++r)
        psum[r] += __shfl_xor(psum[r], d);
#pragma unroll
    for (int r = 0; r < 4; ++r) lrun[r] = lrun[r] * alpha[r] + psum[r];

    // rescale O accumulator
#pragma unroll
    for (int jo = 0; jo < 4; ++jo)
#pragma unroll
      for (int r = 0; r < 4; ++r)
        o[jo][r] = o[jo][r] * alpha[r];

    // same-wave LDS RAW: DS is in-order per wave; fence the compiler + waitcnt
    asm volatile("s_waitcnt lgkmcnt(0)" ::: "memory");

    // O += P V
    bf16x8 pf[2];
#pragma unroll
    for (int h = 0; h < 2; ++h)
      pf[h] = *(const bf16x8*)&Ps[(wave * 16 + lm) * LDF + h * 32 + qd * 8];
#pragma unroll
    for (int jo = 0; jo < 4; ++jo)
#pragma unroll
      for (int h = 0; h < 2; ++h) {
        bf16x8 vf = *(const bf16x8*)&Vs[(jo * 16 + lm) * LDF + h * 32 + qd * 8];
        o[jo] = __builtin_amdgcn_mfma_f32_16x16x32_bf16(pf[h], vf, o[jo], 0, 0, 0);
      }
  }

  // epilogue
  const int b = bh >> 4, hh = bh & 15;
#pragma unroll
  for (int jo = 0; jo < 4; ++jo)
#pragma unroll
    for (int r = 0; r < 4; ++r) {
      int qrow = q0 + wave * 16 + qd * 4 + r;
      float val = o[jo][r] / lrun[r];
      out[(size_t)(b * SEQ + qrow) * DIM + hh * HD + jo * 16 + lm] = val;
    }
}

extern "C" void kernel_launch(void* const* d_in, const int* in_sizes, int n_in,
                              void* d_out, int out_size, void* d_ws, size_t ws_size,
                              hipStream_t stream) {
  const float* x  = (const float*)d_in[0];
  const float* Wq = (const float*)d_in[1];
  const float* bq = (const float*)d_in[2];
  const float* Wk = (const float*)d_in[3];
  const float* bk = (const float*)d_in[4];
  const float* Wv = (const float*)d_in[5];
  const float* bv = (const float*)d_in[6];
  float* out = (float*)d_out;

  unsigned short* ws = (unsigned short*)d_ws;
  const size_t XE = (size_t)BATCH * SEQ * DIM;   // 8388608
  const size_t WE = (size_t)DIM * DIM;           // 1048576
  unsigned short* xb  = ws;
  unsigned short* wqb = xb + XE;
  unsigned short* wkb = wqb + WE;
  unsigned short* wvb = wkb + WE;
  unsigned short* qb  = wvb + WE;
  unsigned short* kb  = qb + XE;
  unsigned short* vb  = kb + XE;

  cast_bf16_kernel<<<(int)(XE / 8 / 256), 256, 0, stream>>>(x,  xb,  (int)(XE / 8));
  cast_bf16_kernel<<<(int)(WE / 8 / 256), 256, 0, stream>>>(Wq, wqb, (int)(WE / 8));
  cast_bf16_kernel<<<(int)(WE / 8 / 256), 256, 0, stream>>>(Wk, wkb, (int)(WE / 8));
  cast_bf16_kernel<<<(int)(WE / 8 / 256), 256, 0, stream>>>(Wv, wvb, (int)(WE / 8));

  dim3 gg(64, 8);
  gemm_qkv<<<gg, 256, 0, stream>>>(xb, wqb, bq, qb, 0);
  gemm_qkv<<<gg, 256, 0, stream>>>(xb, wkb, bk, kb, 0);
  gemm_qkv<<<gg, 256, 0, stream>>>(xb, wvb, bv, vb, 1);

  dim3 fg(SEQ / 64, BATCH * NH);
  flash_kernel<<<fg, 256, 0, stream>>>(qb, kb, vb, out);
}

// Round 2
// 263.140 us; speedup vs baseline: 1.6299x; 1.6299x over previous
//
#include <hip/hip_runtime.h>

typedef __bf16 bf16x8 __attribute__((ext_vector_type(8)));
typedef float f32x4 __attribute__((ext_vector_type(4)));

#define BATCH 4
#define SEQ   2048
#define DIM   1024
#define NH    16
#define HD    64

__device__ __forceinline__ unsigned short f2bf(float f) {
  union { float f; unsigned u; } v; v.f = f;
  unsigned u = v.u;
  u += 0x7FFF + ((u >> 16) & 1);   // round-to-nearest-even
  return (unsigned short)(u >> 16);
}

__device__ __forceinline__ void g2lds16(const unsigned short* g, unsigned short* l) {
  __builtin_amdgcn_global_load_lds(
      (const __attribute__((address_space(1))) unsigned int*)g,
      (__attribute__((address_space(3))) unsigned int*)l, 16, 0, 0);
}

// ---------------- cast fp32 -> bf16, 8 elems/thread ----------------
__global__ __launch_bounds__(256) void cast_bf16_kernel(
    const float* __restrict__ in, unsigned short* __restrict__ out, int n8) {
  int i = blockIdx.x * 256 + threadIdx.x;
  if (i >= n8) return;
  const float4* p = (const float4*)in + (size_t)i * 2;
  float4 a = p[0], b = p[1];
  unsigned short r[8];
  r[0] = f2bf(a.x); r[1] = f2bf(a.y); r[2] = f2bf(a.z); r[3] = f2bf(a.w);
  r[4] = f2bf(b.x); r[5] = f2bf(b.y); r[6] = f2bf(b.z); r[7] = f2bf(b.w);
  *(uint4*)&out[(size_t)i * 8] = *(uint4*)r;
}

// cast the 3 weight matrices in one launch (blockIdx.y selects)
__global__ __launch_bounds__(256) void cast_w_kernel(
    const float* __restrict__ w0, const float* __restrict__ w1,
    const float* __restrict__ w2, unsigned short* __restrict__ o0,
    unsigned short* __restrict__ o1, unsigned short* __restrict__ o2, int n8) {
  const float* in = (blockIdx.y == 0) ? w0 : (blockIdx.y == 1) ? w1 : w2;
  unsigned short* out = (blockIdx.y == 0) ? o0 : (blockIdx.y == 1) ? o1 : o2;
  int i = blockIdx.x * 256 + threadIdx.x;
  if (i >= n8) return;
  const float4* p = (const float4*)in + (size_t)i * 2;
  float4 a = p[0], b = p[1];
  unsigned short r[8];
  r[0] = f2bf(a.x); r[1] = f2bf(a.y); r[2] = f2bf(a.z); r[3] = f2bf(a.w);
  r[4] = f2bf(b.x); r[5] = f2bf(b.y); r[6] = f2bf(b.z); r[7] = f2bf(b.w);
  *(uint4*)&out[(size_t)i * 8] = *(uint4*)r;
}

// ---------------- fused QKV projection GEMM --------------------------
// z=0: Q (store [b,h,s,hd]), z=1: K (same), z=2: V (store [b,h,hd,s]).
// C[m,n] = sum_k A[m,k]*W[n,k] + bias[n]; m97-style global_load_lds staging.
__global__ __launch_bounds__(256) void gemm_qkv(
    const unsigned short* __restrict__ A,
    const unsigned short* __restrict__ Wqp, const unsigned short* __restrict__ Wkp,
    const unsigned short* __restrict__ Wvp,
    const float* __restrict__ bqp, const float* __restrict__ bkp,
    const float* __restrict__ bvp,
    unsigned short* __restrict__ oq, unsigned short* __restrict__ ok,
    unsigned short* __restrict__ ov) {
  __shared__ unsigned short As[128 * 32];
  __shared__ unsigned short Bs[128 * 32];
  const int z = blockIdx.z;
  const unsigned short* W = (z == 0) ? Wqp : (z == 1) ? Wkp : Wvp;
  const float* bias        = (z == 0) ? bqp : (z == 1) ? bkp : bvp;
  unsigned short* outp     = (z == 0) ? oq  : (z == 1) ? ok  : ov;
  const int mode = (z == 2) ? 1 : 0;

  const int tid  = threadIdx.x;
  const int wave = tid >> 6;
  const int lane = tid & 63;
  const int lm   = lane & 15;
  const int qd   = lane >> 4;
  const int m0 = blockIdx.x * 128;
  const int n0 = blockIdx.y * 128;
  const int wm = (wave >> 1) * 64;
  const int wn = (wave & 1) * 64;

  const f32x4 zero = {0.f, 0.f, 0.f, 0.f};
  f32x4 acc[4][4];
#pragma unroll
  for (int i = 0; i < 4; ++i)
#pragma unroll
    for (int j = 0; j < 4; ++j) acc[i][j] = zero;

  const int srow = tid >> 2;          // 0..63
  const int scol = (tid & 3) * 8;     // 0,8,16,24

  for (int kt = 0; kt < DIM; kt += 32) {
    __syncthreads();
    // stage A,B tiles: [128][32] unpadded, lane-contiguous LDS fill
    g2lds16(&A[(size_t)(m0 + srow) * DIM + kt + scol],       &As[(size_t)tid * 8]);
    g2lds16(&A[(size_t)(m0 + 64 + srow) * DIM + kt + scol],  &As[2048 + (size_t)tid * 8]);
    g2lds16(&W[(size_t)(n0 + srow) * DIM + kt + scol],       &Bs[(size_t)tid * 8]);
    g2lds16(&W[(size_t)(n0 + 64 + srow) * DIM + kt + scol],  &Bs[2048 + (size_t)tid * 8]);
    __syncthreads();

    bf16x8 af[4], bfr[4];
#pragma unroll
    for (int i = 0; i < 4; ++i) af[i]  = *(const bf16x8*)&As[(wm + i * 16 + lm) * 32 + qd * 8];
#pragma unroll
    for (int j = 0; j < 4; ++j) bfr[j] = *(const bf16x8*)&Bs[(wn + j * 16 + lm) * 32 + qd * 8];
#pragma unroll
    for (int i = 0; i < 4; ++i)
#pragma unroll
      for (int j = 0; j < 4; ++j)
        acc[i][j] = __builtin_amdgcn_mfma_f32_16x16x32_bf16(af[i], bfr[j], acc[i][j], 0, 0, 0);
  }

  // epilogue: +bias, cast bf16, permuted store
#pragma unroll
  for (int j = 0; j < 4; ++j) {
    int col = n0 + wn + j * 16 + lm;       // n index
    float bb = bias[col];
    int h = col >> 6, hd = col & 63;
#pragma unroll
    for (int i = 0; i < 4; ++i) {
#pragma unroll
      for (int r = 0; r < 4; ++r) {
        int row = m0 + wm + i * 16 + qd * 4 + r;   // m index
        int b = row >> 11, s = row & 2047;
        float v = acc[i][j][r] + bb;
        size_t idx;
        if (mode == 0) idx = ((size_t)(b * NH + h) * SEQ + s) * HD + hd;
        else           idx = ((size_t)(b * NH + h) * HD + hd) * SEQ + s;
        outp[idx] = f2bf(v);
      }
    }
  }
}

// ---------------- flash attention (no-max softmax, S^T trick) --------
// Q,K: [bh, s, hd] bf16.  V: [bh, hd, s] bf16.  out: [b, s, h*hd] fp32.
// Block: 128 q-rows; wave w owns rows [w*32, w*32+32). 32 key-tiles of 64.
#define LDP 72
__global__ __launch_bounds__(256, 4) void flash_kernel(
    const unsigned short* __restrict__ Qw, const unsigned short* __restrict__ Kw,
    const unsigned short* __restrict__ Vw, float* __restrict__ out) {
  __shared__ unsigned short Ks2[2 * 64 * 32];   // [hd_half][key][32]
  __shared__ unsigned short Vs2[2 * 64 * 32];   // [key_half][hd][32]
  __shared__ unsigned short Ps[128 * LDP];      // [qrow][key]
  __shared__ float Ls[128];

  const int tid  = threadIdx.x;
  const int w    = tid >> 6;
  const int lane = tid & 63;
  const int lm   = lane & 15;
  const int qd   = lane >> 4;
  const int bh   = blockIdx.y;
  const int q0   = blockIdx.x * 128;

  const unsigned short* Qbase = Qw + (size_t)bh * (SEQ * HD);
  const unsigned short* Kbase = Kw + (size_t)bh * (SEQ * HD);
  const unsigned short* Vbase = Vw + (size_t)bh * (HD * SEQ);

  // Q fragments in registers: qf[g][h] = Q[q0+w*32+g*16+lm][h*32+qd*8 ..]
  bf16x8 qf[2][2];
#pragma unroll
  for (int g = 0; g < 2; ++g)
#pragma unroll
    for (int h = 0; h < 2; ++h)
      qf[g][h] = *(const bf16x8*)&Qbase[(size_t)(q0 + w * 32 + g * 16 + lm) * HD + h * 32 + qd * 8];

  const f32x4 zero = {0.f, 0.f, 0.f, 0.f};
  f32x4 o[2][4];
#pragma unroll
  for (int g = 0; g < 2; ++g)
#pragma unroll
    for (int jn = 0; jn < 4; ++jn) o[g][jn] = zero;
  float psg[2] = {0.f, 0.f};

  const int srow = tid >> 2;          // 0..63
  const int scol = (tid & 3) * 8;     // 0,8,16,24
  const float EC = 0.18033688f;       // log2(e)/8 : folds the 1/sqrt(64) scale

  for (int kt = 0; kt < SEQ / 64; ++kt) {
    __syncthreads();
    // stage K tile: Ks2[p][key][c] = K[kt*64+key][p*32+c]
    g2lds16(&Kbase[(size_t)(kt * 64 + srow) * HD + scol],      &Ks2[(size_t)tid * 8]);
    g2lds16(&Kbase[(size_t)(kt * 64 + srow) * HD + 32 + scol], &Ks2[2048 + (size_t)tid * 8]);
    // stage V tile: Vs2[p][hd][c] = V^T[hd][kt*64 + p*32 + c]
    g2lds16(&Vbase[(size_t)srow * SEQ + kt * 64 + scol],       &Vs2[(size_t)tid * 8]);
    g2lds16(&Vbase[(size_t)srow * SEQ + kt * 64 + 32 + scol],  &Vs2[2048 + (size_t)tid * 8]);
    __syncthreads();

    // S^T = K Q^T : st[jk][g] has key=jk*16+qd*4+r (rows), qrow=g*16+lm (cols)
#pragma unroll
    for (int jk = 0; jk < 4; ++jk) {
      bf16x8 kf0 = *(const bf16x8*)&Ks2[(jk * 16 + lm) * 32 + qd * 8];
      bf16x8 kf1 = *(const bf16x8*)&Ks2[2048 + (jk * 16 + lm) * 32 + qd * 8];
      f32x4 st[2];
#pragma unroll
      for (int g = 0; g < 2; ++g) {
        st[g] = __builtin_amdgcn_mfma_f32_16x16x32_bf16(kf0, qf[g][0], zero, 0, 0, 0);
        st[g] = __builtin_amdgcn_mfma_f32_16x16x32_bf16(kf1, qf[g][1], st[g], 0, 0, 0);
      }
      // p = exp2(s*log2(e)/8); pack 4 bf16 (trunc) and one b64 write per g
#pragma unroll
      for (int g = 0; g < 2; ++g) {
        float p0 = __builtin_amdgcn_exp2f(st[g][0] * EC);
        float p1 = __builtin_amdgcn_exp2f(st[g][1] * EC);
        float p2 = __builtin_amdgcn_exp2f(st[g][2] * EC);
        float p3 = __builtin_amdgcn_exp2f(st[g][3] * EC);
        psg[g] += (p0 + p1) + (p2 + p3);
        uint2 pk;
        pk.x = __builtin_amdgcn_perm(__float_as_uint(p1), __float_as_uint(p0), 0x07060302);
        pk.y = __builtin_amdgcn_perm(__float_as_uint(p3), __float_as_uint(p2), 0x07060302);
        *(uint2*)&Ps[(w * 32 + g * 16 + lm) * LDP + jk * 16 + qd * 4] = pk;
      }
    }

    // same-wave LDS RAW (wave w only touches its own 32 Ps rows)
    asm volatile("s_waitcnt lgkmcnt(0)" ::: "memory");

    // O += P V   (pf: A-op rows qrow; vf: B-op rows hd)
#pragma unroll
    for (int h2 = 0; h2 < 2; ++h2) {
      bf16x8 pf0 = *(const bf16x8*)&Ps[(w * 32 + lm) * LDP + h2 * 32 + qd * 8];
      bf16x8 pf1 = *(const bf16x8*)&Ps[(w * 32 + 16 + lm) * LDP + h2 * 32 + qd * 8];
#pragma unroll
      for (int jn = 0; jn < 4; ++jn) {
        bf16x8 vf = *(const bf16x8*)&Vs2[h2 * 2048 + (jn * 16 + lm) * 32 + qd * 8];
        o[0][jn] = __builtin_amdgcn_mfma_f32_16x16x32_bf16(pf0, vf, o[0][jn], 0, 0, 0);
        o[1][jn] = __builtin_amdgcn_mfma_f32_16x16x32_bf16(pf1, vf, o[1][jn], 0, 0, 0);
      }
    }
  }

  // final row-sum reduce (over the 4 qd lane-groups) and normalize
  float l0 = psg[0], l1 = psg[1];
  l0 += __shfl_xor(l0, 16); l0 += __shfl_xor(l0, 32);
  l1 += __shfl_xor(l1, 16); l1 += __shfl_xor(l1, 32);
  if (qd == 0) {
    Ls[w * 32 + lm]      = l0;
    Ls[w * 32 + 16 + lm] = l1;
  }
  asm volatile("s_waitcnt lgkmcnt(0)" ::: "memory");

  const int b = bh >> 4, hh = bh & 15;
#pragma unroll
  for (int g = 0; g < 2; ++g)
#pragma unroll
    for (int r = 0; r < 4; ++r) {
      float inv = 1.0f / Ls[w * 32 + g * 16 + qd * 4 + r];
      int qrow = q0 + w * 32 + g * 16 + qd * 4 + r;
#pragma unroll
      for (int jn = 0; jn < 4; ++jn)
        out[(size_t)(b * SEQ + qrow) * DIM + hh * HD + jn * 16 + lm] = o[g][jn][r] * inv;
    }
}

extern "C" void kernel_launch(void* const* d_in, const int* in_sizes, int n_in,
                              void* d_out, int out_size, void* d_ws, size_t ws_size,
                              hipStream_t stream) {
  const float* x  = (const float*)d_in[0];
  const float* Wq = (const float*)d_in[1];
  const float* bq = (const float*)d_in[2];
  const float* Wk = (const float*)d_in[3];
  const float* bk = (const float*)d_in[4];
  const float* Wv = (const float*)d_in[5];
  const float* bv = (const float*)d_in[6];
  float* out = (float*)d_out;

  unsigned short* ws = (unsigned short*)d_ws;
  const size_t XE = (size_t)BATCH * SEQ * DIM;   // 8388608
  const size_t WE = (size_t)DIM * DIM;           // 1048576
  unsigned short* xb  = ws;
  unsigned short* wqb = xb + XE;
  unsigned short* wkb = wqb + WE;
  unsigned short* wvb = wkb + WE;
  unsigned short* qb  = wvb + WE;
  unsigned short* kb  = qb + XE;
  unsigned short* vb  = kb + XE;

  cast_bf16_kernel<<<(int)(XE / 8 / 256), 256, 0, stream>>>(x, xb, (int)(XE / 8));
  dim3 cw((int)(WE / 8 / 256), 3);
  cast_w_kernel<<<cw, 256, 0, stream>>>(Wq, Wk, Wv, wqb, wkb, wvb, (int)(WE / 8));

  dim3 gg(64, 8, 3);
  gemm_qkv<<<gg, 256, 0, stream>>>(xb, wqb, wkb, wvb, bq, bk, bv, qb, kb, vb);

  dim3 fg(SEQ / 128, BATCH * NH);
  flash_kernel<<<fg, 256, 0, stream>>>(qb, kb, vb, out);
}